// Round 16
// baseline (901.006 us; speedup 1.0000x reference)
//
#include <hip/hip_runtime.h>
#include <hip/hip_bf16.h>
#include <math.h>

// LSTM language model. Round 16: (1) recurrence poll merged back to
// load-all+check (the r13 pre-gate added one serialized L3 RT per step);
// (2) one barrier per step (dataflow implies the write-side ordering);
// (3) prep embed re-tiled 2048->256 blocks (8t x 256col) for 16x W reuse.
// Proj path and all layouts byte-identical to round 15.
// ws layout (~58.8 MB):
//   xWb    [128][16][4096] f32      33,554,432 B @ 0
//   ub_hi  [256ct][32kt][64][8] f16  8,388,608 B @ 33,554,432
//          col = ct*16 + (lane&15) (ct = g*64 + bid), k = kt*32+(lane>>4)*8+e
//   ub_lo   (same)                   8,388,608 B @ 41,943,040
//   hslots [129][hi 16384 | lo 16384] ushort = 8,454,144 B @ 50,331,648
//          slot t: h_t fp16 hi/lo, elem(b,j) = (j>>5)*512 + (((j>>3)&3)*16+b)*8
//          + (j&7); slot 0 zeroed (h0), rest poisoned 0xFFFF (fp16 NaN).

#define VOCAB 32000
#define EMBED 256
#define UNITS 1024
#define GATES 4096
#define BATCH 16
#define SEQ 128
#define NB 64   // persistent recurrence blocks (16 cells each, 512 thr)

using s16x8 = __attribute__((ext_vector_type(8))) short;
using f16x8 = __attribute__((ext_vector_type(8))) _Float16;
using f32x4 = __attribute__((ext_vector_type(4))) float;

__device__ __forceinline__ unsigned short f16_bits(float x) {
    _Float16 h = (_Float16)x;                 // v_cvt_f16_f32, RNE
    return __builtin_bit_cast(unsigned short, h);
}
__device__ __forceinline__ float f16_f32(unsigned short b) {
    return (float)__builtin_bit_cast(_Float16, b);
}
__device__ __forceinline__ int swz_e(int r, int k) {
    return (r * 64 + k) ^ ((((r & 7) ^ ((r >> 2) & 7))) << 3);
}
__device__ __forceinline__ unsigned long long ld_u64(const unsigned long long* p) {
    return __hip_atomic_load(p, __ATOMIC_RELAXED, __HIP_MEMORY_SCOPE_AGENT);
}
__device__ __forceinline__ unsigned poison_u64(unsigned long long v) {
    return (unsigned)((unsigned)v == 0xFFFFFFFFu) |
           (unsigned)((unsigned)(v >> 32) == 0xFFFFFFFFu);
}

// ---------- K0: merged prep — blocks 0..255: U -> fp16 hi/lo fragments;
// blocks 256..511: xWb = emb@W + bias, t-tiled (8 t x 256 col per block) ----
__global__ void __launch_bounds__(256) k_prep(
    const float* __restrict__ U,
    unsigned short* __restrict__ ub_hi,
    unsigned short* __restrict__ ub_lo,
    const int* __restrict__ inputs,
    const float* __restrict__ emb,
    const float* __restrict__ W,
    const float* __restrict__ bias,
    float* __restrict__ xWb) {
    __shared__ __align__(16) char smem_raw[65536];
    const int tid = threadIdx.x;

    if (blockIdx.x < 256) {
        // ---- U conversion (r13 layout) ----
        float* lds_u = (float*)smem_raw;       // [k][16 cols], 64 KB
        const int ct = blockIdx.x;
        for (int k = tid; k < 1024; k += 256) {
            const float4* src = (const float4*)(U + (size_t)k * GATES + ct * 16);
            float4* dst = (float4*)(&lds_u[k * 16]);
            dst[0] = src[0]; dst[1] = src[1]; dst[2] = src[2]; dst[3] = src[3];
        }
        __syncthreads();
        const int lane = tid & 63;
        const int coll = lane & 15;
        const int kg = lane >> 4;
        for (int kt = (tid >> 6); kt < 32; kt += 4) {
            const int ks = kt * 32 + kg * 8;
            unsigned short h8[8], l8[8];
#pragma unroll
            for (int e = 0; e < 8; ++e) {
                float v = lds_u[(ks + e) * 16 + coll];
                unsigned short hb = f16_bits(v);
                h8[e] = hb;
                l8[e] = f16_bits(v - f16_f32(hb));
            }
            size_t o = (((size_t)ct * 32 + kt) * 64 + lane) * 8;
            *(s16x8*)(ub_hi + o) = *(const s16x8*)h8;
            *(s16x8*)(ub_lo + o) = *(const s16x8*)l8;
        }
        return;
    }

    // ---- embed + xW, t-tiled: block = (tb, ct2); 8 t's share W col-tile ----
    const int eb  = blockIdx.x - 256;          // 0..255
    const int ct2 = eb & 15;                   // col-tile (256 cols)
    const int tb  = eb >> 4;                   // t-tile (8 t's)
    const int col = ct2 * 256 + tid;
    float (*xs)[EMBED] = (float (*)[EMBED])smem_raw;   // [16][256] f32, 16 KB
    int* toks = (int*)(smem_raw + 16384);

    for (int tt = 0; tt < 8; ++tt) {
        const int t = tb * 8 + tt;
        __syncthreads();                       // prior iteration's xs reads done
        if (tid < BATCH)
            toks[tid] = inputs[tid * SEQ + t];
        __syncthreads();
        for (int r = 0; r < BATCH; ++r)
            xs[r][tid] = emb[(size_t)toks[r] * EMBED + tid];
        __syncthreads();
        float acc[BATCH];
#pragma unroll
        for (int r = 0; r < BATCH; ++r) acc[r] = 0.f;
        for (int k = 0; k < EMBED; ++k) {
            float w = W[(size_t)k * GATES + col];
#pragma unroll
            for (int r = 0; r < BATCH; ++r) acc[r] += xs[r][k] * w;
        }
        const float bb = bias[col];
#pragma unroll
        for (int r = 0; r < BATCH; ++r)
            xWb[((size_t)t * BATCH + r) * GATES + col] = acc[r] + bb;
    }
}

// ---------- K2: FUSED, 512 threads (8 waves) -------------------------------
// blocks 0..63: recurrence, 16 cells each; wave w covers k in [128w,128w+128)
// blocks 64..4063: projection 128x128, 8-wave split, mt2-major order.
__global__ void __launch_bounds__(512, 2) k_fused(
    const unsigned short* __restrict__ ub_hi,
    const unsigned short* __restrict__ ub_lo,
    const float* __restrict__ xWb,
    unsigned short* __restrict__ hsl,
    const float* __restrict__ Wc,
    const float* __restrict__ bc,
    float* __restrict__ out) {
    __shared__ __align__(16) char smem_raw[32768];
    const int tid  = threadIdx.x;
    const int lane = tid & 63;
    const int w    = tid >> 6;            // wave 0..7

    if (blockIdx.x < NB) {
        // ================= recurrence path =================
        __builtin_amdgcn_s_setprio(1);
        float (*zpart)[4][256] = (float (*)[4][256])smem_raw;  // [8][4][256] 32KB
        const int bid = blockIdx.x;
        const int j0  = bid * 16;

        const int b_own  = (tid >> 4) & 15;    // owners are tid<256
        const int jj_own = tid & 15;
        const int j_own  = j0 + jj_own;
        const int hb_e = ((j_own >> 5) * 512) + (((j_own >> 3) & 3) * 16 + b_own) * 8 + (j_own & 7);
        float c_own = 0.f;

        // preload U fragments (once): 4 gc-tiles x 4 kt per wave = 128 VGPR
        f16x8 Uh[4][4], Ul[4][4];
#pragma unroll
        for (int g = 0; g < 4; ++g)
#pragma unroll
            for (int q = 0; q < 4; ++q) {
                size_t o = (((size_t)(g * 64 + bid) * 32) + (w * 4 + q)) * 512 + lane * 8;
                Uh[g][q] = *(const f16x8*)(ub_hi + o);
                Ul[g][q] = *(const f16x8*)(ub_lo + o);
            }

        for (int t = 0; t < SEQ; ++t) {
            float xw0 = 0.f, xw1 = 0.f, xw2 = 0.f, xw3 = 0.f;
            if (tid < 256) {
                const float* xwp = xWb + ((size_t)t * BATCH + b_own) * GATES + j_own;
                xw0 = xwp[0]; xw1 = xwp[UNITS]; xw2 = xwp[2 * UNITS]; xw3 = xwp[3 * UNITS];
            }

            const unsigned long long* p64 =
                (const unsigned long long*)(hsl + (size_t)t * 32768);

            // ---- merged poll: the detecting load IS the data load ----
            union HU { unsigned long long q2[2]; f16x8 v; };
            HU hh[4], hl[4];
            while (true) {
                unsigned bad = 0;
#pragma unroll
                for (int q = 0; q < 4; ++q) {
                    const size_t u = (size_t)(w * 4 + q) * 128 + lane * 2;
                    hh[q].q2[0] = ld_u64(p64 + u);
                    hh[q].q2[1] = ld_u64(p64 + u + 1);
                    hl[q].q2[0] = ld_u64(p64 + 4096 + u);
                    hl[q].q2[1] = ld_u64(p64 + 4097 + u);
                }
#pragma unroll
                for (int q = 0; q < 4; ++q)
                    bad |= poison_u64(hh[q].q2[0]) | poison_u64(hh[q].q2[1]) |
                           poison_u64(hl[q].q2[0]) | poison_u64(hl[q].q2[1]);
                if (__all((int)(bad == 0))) break;
                __builtin_amdgcn_s_sleep(8);
            }

            f32x4 a0[4], a1[4], a2[4];
#pragma unroll
            for (int g = 0; g < 4; ++g) {
                a0[g] = (f32x4){0.f, 0.f, 0.f, 0.f};
                a1[g] = (f32x4){0.f, 0.f, 0.f, 0.f};
                a2[g] = (f32x4){0.f, 0.f, 0.f, 0.f};
            }
#pragma unroll
            for (int q = 0; q < 4; ++q)
#pragma unroll
                for (int g = 0; g < 4; ++g) {
                    a0[g] = __builtin_amdgcn_mfma_f32_16x16x32_f16(hh[q].v, Uh[g][q], a0[g], 0, 0, 0);
                    a1[g] = __builtin_amdgcn_mfma_f32_16x16x32_f16(hh[q].v, Ul[g][q], a1[g], 0, 0, 0);
                    a2[g] = __builtin_amdgcn_mfma_f32_16x16x32_f16(hl[q].v, Uh[g][q], a2[g], 0, 0, 0);
                }

            // single-buffer zpart is safe with ONE barrier: any wave's next-
            // step zpart write is ordered after poll(t+1) success, which
            // requires this block's owners to have stored h(t+1), which
            // happens only after their zpart(t) reads completed.
#pragma unroll
            for (int g = 0; g < 4; ++g)
#pragma unroll
                for (int r = 0; r < 4; ++r)
                    zpart[w][g][((lane >> 4) * 4 + r) * 16 + (lane & 15)] =
                        a0[g][r] + a1[g][r] + a2[g][r];
            __syncthreads();

            if (tid < 256) {
                const int zi_idx = b_own * 16 + jj_own;
                float zi = xw0, zf = xw1, zg = xw2, zo = xw3;
#pragma unroll
                for (int ww = 0; ww < 8; ++ww) {
                    zi += zpart[ww][0][zi_idx];
                    zf += zpart[ww][1][zi_idx];
                    zg += zpart[ww][2][zi_idx];
                    zo += zpart[ww][3][zi_idx];
                }
                float si = 1.f / (1.f + expf(-zi));
                float sf = 1.f / (1.f + expf(-zf));
                float so = 1.f / (1.f + expf(-zo));
                float c_new = sf * c_own + si * tanhf(zg);
                float h_new = so * tanhf(c_new);
                c_own = c_new;

                int hhi = (int)f16_bits(h_new);
                int hlo = (int)f16_bits(h_new - f16_f32((unsigned short)hhi));
                int hhi_nb = __shfl_xor(hhi, 1);
                int hlo_nb = __shfl_xor(hlo, 1);
                unsigned short* nh = hsl + (size_t)(t + 1) * 32768;
                if ((tid & 1) == 0) {   // jj even -> adjacent pair 4B-aligned
                    unsigned hp = (unsigned)(unsigned short)hhi | ((unsigned)(unsigned short)hhi_nb << 16);
                    unsigned lp = (unsigned)(unsigned short)hlo | ((unsigned)(unsigned short)hlo_nb << 16);
                    __hip_atomic_store((unsigned*)(nh + hb_e), hp,
                                       __ATOMIC_RELAXED, __HIP_MEMORY_SCOPE_AGENT);
                    __hip_atomic_store((unsigned*)(nh + 16384 + hb_e), lp,
                                       __ATOMIC_RELAXED, __HIP_MEMORY_SCOPE_AGENT);
                }
            }
            // no trailing barrier: next step's poll provides ordering.
        }
        return;
    }

    // ================= projection path (8-wave, mt2-major) =================
    unsigned short* Bs = (unsigned short*)smem_raw;   // fp16 bits, 16 KB
    const int bidp = blockIdx.x - NB;                 // 0..3999
    const int mt2 = bidp / 250;                       // t-group, ASCENDING
    const int nt  = bidp % 250;
    const int n0 = nt * 128;

    // ---- gate on slot (mt2*8+8) fully non-poison ----
    {
        const unsigned long long* gp =
            (const unsigned long long*)(hsl + (size_t)(mt2 * 8 + 8) * 32768);
        {
            const unsigned long long* sp = gp + (size_t)tid * 8;   // 512*8=4096
            unsigned long long v = ld_u64(sp);
            while (poison_u64(v)) {
                __builtin_amdgcn_s_sleep(32);
                v = ld_u64(sp);
            }
        }
        while (true) {
            unsigned bad = 0;
#pragma unroll
            for (int i = 0; i < 8; ++i)
                bad |= poison_u64(ld_u64(gp + (size_t)i * 512 + tid));
            if (__syncthreads_and((int)(bad == 0))) break;
            __builtin_amdgcn_s_sleep(16);
        }
        asm volatile("" ::: "memory");
    }

    // wave split: wmt = (w>>2)*4 t-rows, wn = (w&3)*32 n-cols
    const int b_kb  = (tid >> 5) * 8;     // staging coords (tid<256 only)
    const int b_nb4 = (tid & 31) * 4;
    const int wmt  = (w >> 2) * 4;
    const int wn   = (w & 3) * 32;
    const int lr   = lane & 15;
    const int kg   = lane >> 4;

    f32x4 acc[4][2];                      // [mi -> t][ni]
#pragma unroll
    for (int i = 0; i < 4; ++i)
#pragma unroll
        for (int j = 0; j < 2; ++j) acc[i][j] = (f32x4){0.f, 0.f, 0.f, 0.f};

    const unsigned short* aslot[4];
#pragma unroll
    for (int mi = 0; mi < 4; ++mi)
        aslot[mi] = hsl + (size_t)(mt2 * 8 + wmt + mi + 1) * 32768 + lane * 8;

    f16x8 A0h[4], A0l[4], A1h[4], A1l[4];
#pragma unroll
    for (int mi = 0; mi < 4; ++mi) {
        A0h[mi] = *(const f16x8*)(aslot[mi]);
        A0l[mi] = *(const f16x8*)(aslot[mi] + 16384);
        A1h[mi] = *(const f16x8*)(aslot[mi] + 512);
        A1l[mi] = *(const f16x8*)(aslot[mi] + 512 + 16384);
    }
    float4 rawB[8];
    if (tid < 256) {
#pragma unroll
        for (int i = 0; i < 8; ++i)
            rawB[i] = *(const float4*)(Wc + (size_t)(b_kb + i) * VOCAB + n0 + b_nb4);
    }

    for (int kt = 0; kt < 16; ++kt) {
        __syncthreads();
        if (tid < 256) {
#pragma unroll
            for (int nn = 0; nn < 4; ++nn) {
                unsigned short h8[8];
#pragma unroll
                for (int i = 0; i < 8; ++i)
                    h8[i] = f16_bits(((const float*)&rawB[i])[nn]);
                int e = swz_e(b_nb4 + nn, b_kb);
                *(s16x8*)(&Bs[e]) = *(const s16x8*)h8;
            }
        }
        __syncthreads();
        if (kt < 15 && tid < 256) {
            const int k0n = (kt + 1) * 64;
#pragma unroll
            for (int i = 0; i < 8; ++i)
                rawB[i] = *(const float4*)(Wc + (size_t)(k0n + b_kb + i) * VOCAB + n0 + b_nb4);
        }
        // ks = 0
        {
            f16x8 bh[2];
#pragma unroll
            for (int ni = 0; ni < 2; ++ni)
                bh[ni] = *(const f16x8*)(&Bs[swz_e(wn + ni * 16 + lr, kg * 8)]);
#pragma unroll
            for (int mi = 0; mi < 4; ++mi)
#pragma unroll
                for (int ni = 0; ni < 2; ++ni) {
                    acc[mi][ni] = __builtin_amdgcn_mfma_f32_16x16x32_f16(A0h[mi], bh[ni], acc[mi][ni], 0, 0, 0);
                    acc[mi][ni] = __builtin_amdgcn_mfma_f32_16x16x32_f16(A0l[mi], bh[ni], acc[mi][ni], 0, 0, 0);
                }
            if (kt < 15) {
                const int base = (kt + 1) * 1024;
#pragma unroll
                for (int mi = 0; mi < 4; ++mi) {
                    A0h[mi] = *(const f16x8*)(aslot[mi] + base);
                    A0l[mi] = *(const f16x8*)(aslot[mi] + base + 16384);
                }
            }
        }
        // ks = 1
        {
            f16x8 bh[2];
#pragma unroll
            for (int ni = 0; ni < 2; ++ni)
                bh[ni] = *(const f16x8*)(&Bs[swz_e(wn + ni * 16 + lr, 32 + kg * 8)]);
#pragma unroll
            for (int mi = 0; mi < 4; ++mi)
#pragma unroll
                for (int ni = 0; ni < 2; ++ni) {
                    acc[mi][ni] = __builtin_amdgcn_mfma_f32_16x16x32_f16(A1h[mi], bh[ni], acc[mi][ni], 0, 0, 0);
                    acc[mi][ni] = __builtin_amdgcn_mfma_f32_16x16x32_f16(A1l[mi], bh[ni], acc[mi][ni], 0, 0, 0);
                }
            if (kt < 15) {
                const int base = (kt + 1) * 1024 + 512;
#pragma unroll
                for (int mi = 0; mi < 4; ++mi) {
                    A1h[mi] = *(const f16x8*)(aslot[mi] + base);
                    A1l[mi] = *(const f16x8*)(aslot[mi] + base + 16384);
                }
            }
        }
    }

    float bcv[2];
#pragma unroll
    for (int ni = 0; ni < 2; ++ni) bcv[ni] = bc[n0 + wn + ni * 16 + lr];
#pragma unroll
    for (int mi = 0; mi < 4; ++mi) {
        const int trow = mt2 * 8 + wmt + mi;
#pragma unroll
        for (int ni = 0; ni < 2; ++ni) {
#pragma unroll
            for (int r = 0; r < 4; ++r) {
                int grow = (kg * 4 + r) * 128 + trow;     // m = b*128 + t
                int gcol = n0 + wn + ni * 16 + lr;
                out[(size_t)grow * VOCAB + gcol] = acc[mi][ni][r] + bcv[ni];
            }
        }
    }
}

extern "C" void kernel_launch(void* const* d_in, const int* in_sizes, int n_in,
                              void* d_out, int out_size, void* d_ws, size_t ws_size,
                              hipStream_t stream) {
    const int*   inputs = (const int*)d_in[0];   // int32 (JAX x64 disabled)
    const float* emb  = (const float*)d_in[1];
    const float* W    = (const float*)d_in[2];
    const float* U    = (const float*)d_in[3];
    const float* bias = (const float*)d_in[4];
    const float* Wc   = (const float*)d_in[5];
    const float* bc   = (const float*)d_in[6];
    float* out = (float*)d_out;

    char* ws = (char*)d_ws;
    float*          xWb   = (float*)(ws + 0);
    unsigned short* ub_hi = (unsigned short*)(ws + 33554432);
    unsigned short* ub_lo = (unsigned short*)(ws + 41943040);
    unsigned short* hsl   = (unsigned short*)(ws + 50331648);

    // slot 0 = h0 = 0 (valid); slots 1..128 poisoned 0xFFFF — every call
    hipMemsetAsync(hsl, 0, 65536, stream);
    hipMemsetAsync((char*)hsl + 65536, 0xFF, 8454144 - 65536, stream);

    k_prep<<<512, 256, 0, stream>>>(U, ub_hi, ub_lo,
                                    inputs, emb, W, bias, xWb);
    k_fused<<<NB + 4000, 512, 0, stream>>>(ub_hi, ub_lo, xWb, hsl, Wc, bc, out);
}

// Round 17
// 731.693 us; speedup vs baseline: 1.2314x; 1.2314x over previous
//
#include <hip/hip_runtime.h>
#include <hip/hip_bf16.h>
#include <math.h>

// LSTM language model. Round 17: (1) prep embed reverted to r15's 2048-block
// form (r16 re-tile cost ~67us of prep critical path); (2) proj epilogue uses
// NONTEMPORAL stores (262MB out stream was evicting Wc + h-slots from L3);
// (3) proj drops the A-lo pass (error budget: +2.3e-4 on top of 2.44e-4,
// still 2.3x under threshold) -> half the proj MFMAs and A loads.
// Recurrence path byte-identical to round 16 (merged poll, single barrier).
// ws layout (~58.8 MB):
//   xWb    [128][16][4096] f32      33,554,432 B @ 0
//   ub_hi  [256ct][32kt][64][8] f16  8,388,608 B @ 33,554,432
//   ub_lo   (same)                   8,388,608 B @ 41,943,040
//   hslots [129][hi 16384 | lo 16384] ushort = 8,454,144 B @ 50,331,648
//          slot t: h_t fp16 hi/lo, elem(b,j) = (j>>5)*512 + (((j>>3)&3)*16+b)*8
//          + (j&7); slot 0 zeroed (h0), rest poisoned 0xFFFF (fp16 NaN).

#define VOCAB 32000
#define EMBED 256
#define UNITS 1024
#define GATES 4096
#define BATCH 16
#define SEQ 128
#define NB 64   // persistent recurrence blocks (16 cells each, 512 thr)

using s16x8 = __attribute__((ext_vector_type(8))) short;
using f16x8 = __attribute__((ext_vector_type(8))) _Float16;
using f32x4 = __attribute__((ext_vector_type(4))) float;

__device__ __forceinline__ unsigned short f16_bits(float x) {
    _Float16 h = (_Float16)x;                 // v_cvt_f16_f32, RNE
    return __builtin_bit_cast(unsigned short, h);
}
__device__ __forceinline__ float f16_f32(unsigned short b) {
    return (float)__builtin_bit_cast(_Float16, b);
}
__device__ __forceinline__ int swz_e(int r, int k) {
    return (r * 64 + k) ^ ((((r & 7) ^ ((r >> 2) & 7))) << 3);
}
__device__ __forceinline__ unsigned long long ld_u64(const unsigned long long* p) {
    return __hip_atomic_load(p, __ATOMIC_RELAXED, __HIP_MEMORY_SCOPE_AGENT);
}
__device__ __forceinline__ unsigned poison_u64(unsigned long long v) {
    return (unsigned)((unsigned)v == 0xFFFFFFFFu) |
           (unsigned)((unsigned)(v >> 32) == 0xFFFFFFFFu);
}

// ---------- K0: merged prep — blocks 0..255: U -> fp16 hi/lo fragments;
// blocks 256..2303: xWb = emb@W + bias (r15 form, 1 t per block) ----------
__global__ void __launch_bounds__(256) k_prep(
    const float* __restrict__ U,
    unsigned short* __restrict__ ub_hi,
    unsigned short* __restrict__ ub_lo,
    const int* __restrict__ inputs,
    const float* __restrict__ emb,
    const float* __restrict__ W,
    const float* __restrict__ bias,
    float* __restrict__ xWb) {
    __shared__ __align__(16) char smem_raw[65536];
    const int tid = threadIdx.x;

    if (blockIdx.x < 256) {
        // ---- U conversion (r13 layout) ----
        float* lds_u = (float*)smem_raw;       // [k][16 cols], 64 KB
        const int ct = blockIdx.x;
        for (int k = tid; k < 1024; k += 256) {
            const float4* src = (const float4*)(U + (size_t)k * GATES + ct * 16);
            float4* dst = (float4*)(&lds_u[k * 16]);
            dst[0] = src[0]; dst[1] = src[1]; dst[2] = src[2]; dst[3] = src[3];
        }
        __syncthreads();
        const int lane = tid & 63;
        const int coll = lane & 15;
        const int kg = lane >> 4;
        for (int kt = (tid >> 6); kt < 32; kt += 4) {
            const int ks = kt * 32 + kg * 8;
            unsigned short h8[8], l8[8];
#pragma unroll
            for (int e = 0; e < 8; ++e) {
                float v = lds_u[(ks + e) * 16 + coll];
                unsigned short hb = f16_bits(v);
                h8[e] = hb;
                l8[e] = f16_bits(v - f16_f32(hb));
            }
            size_t o = (((size_t)ct * 32 + kt) * 64 + lane) * 8;
            *(s16x8*)(ub_hi + o) = *(const s16x8*)h8;
            *(s16x8*)(ub_lo + o) = *(const s16x8*)l8;
        }
        return;
    }

    // ---- embed + xW (r15 form) ----
    const int eb = blockIdx.x - 256;           // 0..2047
    const int t   = eb >> 4;                   // 0..127
    const int col = (eb & 15) * 256 + tid;     // 0..4095
    float (*xs)[EMBED] = (float (*)[EMBED])smem_raw;   // [16][256] f32, 16 KB
    int* toks = (int*)(smem_raw + 16384);
    if (tid < BATCH)
        toks[tid] = inputs[tid * SEQ + t];
    __syncthreads();
    for (int r = 0; r < BATCH; ++r)
        xs[r][tid] = emb[(size_t)toks[r] * EMBED + tid];
    __syncthreads();
    float acc[BATCH];
#pragma unroll
    for (int r = 0; r < BATCH; ++r) acc[r] = 0.f;
    for (int k = 0; k < EMBED; ++k) {
        float w = W[(size_t)k * GATES + col];
#pragma unroll
        for (int r = 0; r < BATCH; ++r) acc[r] += xs[r][k] * w;
    }
    const float bb = bias[col];
#pragma unroll
    for (int r = 0; r < BATCH; ++r)
        xWb[((size_t)t * BATCH + r) * GATES + col] = acc[r] + bb;
}

// ---------- K2: FUSED, 512 threads (8 waves) -------------------------------
// blocks 0..63: recurrence, 16 cells each; wave w covers k in [128w,128w+128)
// blocks 64..4063: projection 128x128, 8-wave split, mt2-major order.
__global__ void __launch_bounds__(512, 2) k_fused(
    const unsigned short* __restrict__ ub_hi,
    const unsigned short* __restrict__ ub_lo,
    const float* __restrict__ xWb,
    unsigned short* __restrict__ hsl,
    const float* __restrict__ Wc,
    const float* __restrict__ bc,
    float* __restrict__ out) {
    __shared__ __align__(16) char smem_raw[32768];
    const int tid  = threadIdx.x;
    const int lane = tid & 63;
    const int w    = tid >> 6;            // wave 0..7

    if (blockIdx.x < NB) {
        // ================= recurrence path (r16 body) =================
        __builtin_amdgcn_s_setprio(1);
        float (*zpart)[4][256] = (float (*)[4][256])smem_raw;  // [8][4][256] 32KB
        const int bid = blockIdx.x;
        const int j0  = bid * 16;

        const int b_own  = (tid >> 4) & 15;    // owners are tid<256
        const int jj_own = tid & 15;
        const int j_own  = j0 + jj_own;
        const int hb_e = ((j_own >> 5) * 512) + (((j_own >> 3) & 3) * 16 + b_own) * 8 + (j_own & 7);
        float c_own = 0.f;

        // preload U fragments (once): 4 gc-tiles x 4 kt per wave = 128 VGPR
        f16x8 Uh[4][4], Ul[4][4];
#pragma unroll
        for (int g = 0; g < 4; ++g)
#pragma unroll
            for (int q = 0; q < 4; ++q) {
                size_t o = (((size_t)(g * 64 + bid) * 32) + (w * 4 + q)) * 512 + lane * 8;
                Uh[g][q] = *(const f16x8*)(ub_hi + o);
                Ul[g][q] = *(const f16x8*)(ub_lo + o);
            }

        for (int t = 0; t < SEQ; ++t) {
            float xw0 = 0.f, xw1 = 0.f, xw2 = 0.f, xw3 = 0.f;
            if (tid < 256) {
                const float* xwp = xWb + ((size_t)t * BATCH + b_own) * GATES + j_own;
                xw0 = xwp[0]; xw1 = xwp[UNITS]; xw2 = xwp[2 * UNITS]; xw3 = xwp[3 * UNITS];
            }

            const unsigned long long* p64 =
                (const unsigned long long*)(hsl + (size_t)t * 32768);

            // ---- merged poll: the detecting load IS the data load ----
            union HU { unsigned long long q2[2]; f16x8 v; };
            HU hh[4], hl[4];
            while (true) {
                unsigned bad = 0;
#pragma unroll
                for (int q = 0; q < 4; ++q) {
                    const size_t u = (size_t)(w * 4 + q) * 128 + lane * 2;
                    hh[q].q2[0] = ld_u64(p64 + u);
                    hh[q].q2[1] = ld_u64(p64 + u + 1);
                    hl[q].q2[0] = ld_u64(p64 + 4096 + u);
                    hl[q].q2[1] = ld_u64(p64 + 4097 + u);
                }
#pragma unroll
                for (int q = 0; q < 4; ++q)
                    bad |= poison_u64(hh[q].q2[0]) | poison_u64(hh[q].q2[1]) |
                           poison_u64(hl[q].q2[0]) | poison_u64(hl[q].q2[1]);
                if (__all((int)(bad == 0))) break;
                __builtin_amdgcn_s_sleep(8);
            }

            f32x4 a0[4], a1[4], a2[4];
#pragma unroll
            for (int g = 0; g < 4; ++g) {
                a0[g] = (f32x4){0.f, 0.f, 0.f, 0.f};
                a1[g] = (f32x4){0.f, 0.f, 0.f, 0.f};
                a2[g] = (f32x4){0.f, 0.f, 0.f, 0.f};
            }
#pragma unroll
            for (int q = 0; q < 4; ++q)
#pragma unroll
                for (int g = 0; g < 4; ++g) {
                    a0[g] = __builtin_amdgcn_mfma_f32_16x16x32_f16(hh[q].v, Uh[g][q], a0[g], 0, 0, 0);
                    a1[g] = __builtin_amdgcn_mfma_f32_16x16x32_f16(hh[q].v, Ul[g][q], a1[g], 0, 0, 0);
                    a2[g] = __builtin_amdgcn_mfma_f32_16x16x32_f16(hl[q].v, Uh[g][q], a2[g], 0, 0, 0);
                }

            // single-buffer zpart, ONE barrier (dataflow implies write-order)
#pragma unroll
            for (int g = 0; g < 4; ++g)
#pragma unroll
                for (int r = 0; r < 4; ++r)
                    zpart[w][g][((lane >> 4) * 4 + r) * 16 + (lane & 15)] =
                        a0[g][r] + a1[g][r] + a2[g][r];
            __syncthreads();

            if (tid < 256) {
                const int zi_idx = b_own * 16 + jj_own;
                float zi = xw0, zf = xw1, zg = xw2, zo = xw3;
#pragma unroll
                for (int ww = 0; ww < 8; ++ww) {
                    zi += zpart[ww][0][zi_idx];
                    zf += zpart[ww][1][zi_idx];
                    zg += zpart[ww][2][zi_idx];
                    zo += zpart[ww][3][zi_idx];
                }
                float si = 1.f / (1.f + expf(-zi));
                float sf = 1.f / (1.f + expf(-zf));
                float so = 1.f / (1.f + expf(-zo));
                float c_new = sf * c_own + si * tanhf(zg);
                float h_new = so * tanhf(c_new);
                c_own = c_new;

                int hhi = (int)f16_bits(h_new);
                int hlo = (int)f16_bits(h_new - f16_f32((unsigned short)hhi));
                int hhi_nb = __shfl_xor(hhi, 1);
                int hlo_nb = __shfl_xor(hlo, 1);
                unsigned short* nh = hsl + (size_t)(t + 1) * 32768;
                if ((tid & 1) == 0) {   // jj even -> adjacent pair 4B-aligned
                    unsigned hp = (unsigned)(unsigned short)hhi | ((unsigned)(unsigned short)hhi_nb << 16);
                    unsigned lp = (unsigned)(unsigned short)hlo | ((unsigned)(unsigned short)hlo_nb << 16);
                    __hip_atomic_store((unsigned*)(nh + hb_e), hp,
                                       __ATOMIC_RELAXED, __HIP_MEMORY_SCOPE_AGENT);
                    __hip_atomic_store((unsigned*)(nh + 16384 + hb_e), lp,
                                       __ATOMIC_RELAXED, __HIP_MEMORY_SCOPE_AGENT);
                }
            }
            // no trailing barrier: next step's poll provides ordering.
        }
        return;
    }

    // ================= projection path (8-wave, mt2-major) =================
    // A = h hi ONLY (fp16 RNE of h): error budget allows dropping the lo pass.
    unsigned short* Bs = (unsigned short*)smem_raw;   // fp16 bits, 16 KB
    const int bidp = blockIdx.x - NB;                 // 0..3999
    const int mt2 = bidp / 250;                       // t-group, ASCENDING
    const int nt  = bidp % 250;
    const int n0 = nt * 128;

    // ---- gate on slot (mt2*8+8) fully non-poison ----
    {
        const unsigned long long* gp =
            (const unsigned long long*)(hsl + (size_t)(mt2 * 8 + 8) * 32768);
        {
            const unsigned long long* sp = gp + (size_t)tid * 8;   // 512*8=4096
            unsigned long long v = ld_u64(sp);
            while (poison_u64(v)) {
                __builtin_amdgcn_s_sleep(32);
                v = ld_u64(sp);
            }
        }
        while (true) {
            unsigned bad = 0;
#pragma unroll
            for (int i = 0; i < 8; ++i)
                bad |= poison_u64(ld_u64(gp + (size_t)i * 512 + tid));
            if (__syncthreads_and((int)(bad == 0))) break;
            __builtin_amdgcn_s_sleep(16);
        }
        asm volatile("" ::: "memory");
    }

    // wave split: wmt = (w>>2)*4 t-rows, wn = (w&3)*32 n-cols
    const int b_kb  = (tid >> 5) * 8;     // staging coords (tid<256 only)
    const int b_nb4 = (tid & 31) * 4;
    const int wmt  = (w >> 2) * 4;
    const int wn   = (w & 3) * 32;
    const int lr   = lane & 15;
    const int kg   = lane >> 4;

    f32x4 acc[4][2];                      // [mi -> t][ni]
#pragma unroll
    for (int i = 0; i < 4; ++i)
#pragma unroll
        for (int j = 0; j < 2; ++j) acc[i][j] = (f32x4){0.f, 0.f, 0.f, 0.f};

    const unsigned short* aslot[4];
#pragma unroll
    for (int mi = 0; mi < 4; ++mi)
        aslot[mi] = hsl + (size_t)(mt2 * 8 + wmt + mi + 1) * 32768 + lane * 8;

    f16x8 A0h[4], A1h[4];
#pragma unroll
    for (int mi = 0; mi < 4; ++mi) {
        A0h[mi] = *(const f16x8*)(aslot[mi]);
        A1h[mi] = *(const f16x8*)(aslot[mi] + 512);
    }
    float4 rawB[8];
    if (tid < 256) {
#pragma unroll
        for (int i = 0; i < 8; ++i)
            rawB[i] = *(const float4*)(Wc + (size_t)(b_kb + i) * VOCAB + n0 + b_nb4);
    }

    for (int kt = 0; kt < 16; ++kt) {
        __syncthreads();
        if (tid < 256) {
#pragma unroll
            for (int nn = 0; nn < 4; ++nn) {
                unsigned short h8[8];
#pragma unroll
                for (int i = 0; i < 8; ++i)
                    h8[i] = f16_bits(((const float*)&rawB[i])[nn]);
                int e = swz_e(b_nb4 + nn, b_kb);
                *(s16x8*)(&Bs[e]) = *(const s16x8*)h8;
            }
        }
        __syncthreads();
        if (kt < 15 && tid < 256) {
            const int k0n = (kt + 1) * 64;
#pragma unroll
            for (int i = 0; i < 8; ++i)
                rawB[i] = *(const float4*)(Wc + (size_t)(k0n + b_kb + i) * VOCAB + n0 + b_nb4);
        }
        // ks = 0
        {
            f16x8 bh[2];
#pragma unroll
            for (int ni = 0; ni < 2; ++ni)
                bh[ni] = *(const f16x8*)(&Bs[swz_e(wn + ni * 16 + lr, kg * 8)]);
#pragma unroll
            for (int mi = 0; mi < 4; ++mi)
#pragma unroll
                for (int ni = 0; ni < 2; ++ni)
                    acc[mi][ni] = __builtin_amdgcn_mfma_f32_16x16x32_f16(A0h[mi], bh[ni], acc[mi][ni], 0, 0, 0);
            if (kt < 15) {
                const int base = (kt + 1) * 1024;
#pragma unroll
                for (int mi = 0; mi < 4; ++mi)
                    A0h[mi] = *(const f16x8*)(aslot[mi] + base);
            }
        }
        // ks = 1
        {
            f16x8 bh[2];
#pragma unroll
            for (int ni = 0; ni < 2; ++ni)
                bh[ni] = *(const f16x8*)(&Bs[swz_e(wn + ni * 16 + lr, 32 + kg * 8)]);
#pragma unroll
            for (int mi = 0; mi < 4; ++mi)
#pragma unroll
                for (int ni = 0; ni < 2; ++ni)
                    acc[mi][ni] = __builtin_amdgcn_mfma_f32_16x16x32_f16(A1h[mi], bh[ni], acc[mi][ni], 0, 0, 0);
            if (kt < 15) {
                const int base = (kt + 1) * 1024 + 512;
#pragma unroll
                for (int mi = 0; mi < 4; ++mi)
                    A1h[mi] = *(const f16x8*)(aslot[mi] + base);
            }
        }
    }

    // ---- epilogue: nontemporal stores (out never re-read; keep L3 for Wc/h)
    float bcv[2];
#pragma unroll
    for (int ni = 0; ni < 2; ++ni) bcv[ni] = bc[n0 + wn + ni * 16 + lr];
#pragma unroll
    for (int mi = 0; mi < 4; ++mi) {
        const int trow = mt2 * 8 + wmt + mi;
#pragma unroll
        for (int ni = 0; ni < 2; ++ni) {
#pragma unroll
            for (int r = 0; r < 4; ++r) {
                int grow = (kg * 4 + r) * 128 + trow;     // m = b*128 + t
                int gcol = n0 + wn + ni * 16 + lr;
                __builtin_nontemporal_store(acc[mi][ni][r] + bcv[ni],
                                            &out[(size_t)grow * VOCAB + gcol]);
            }
        }
    }
}

extern "C" void kernel_launch(void* const* d_in, const int* in_sizes, int n_in,
                              void* d_out, int out_size, void* d_ws, size_t ws_size,
                              hipStream_t stream) {
    const int*   inputs = (const int*)d_in[0];   // int32 (JAX x64 disabled)
    const float* emb  = (const float*)d_in[1];
    const float* W    = (const float*)d_in[2];
    const float* U    = (const float*)d_in[3];
    const float* bias = (const float*)d_in[4];
    const float* Wc   = (const float*)d_in[5];
    const float* bc   = (const float*)d_in[6];
    float* out = (float*)d_out;

    char* ws = (char*)d_ws;
    float*          xWb   = (float*)(ws + 0);
    unsigned short* ub_hi = (unsigned short*)(ws + 33554432);
    unsigned short* ub_lo = (unsigned short*)(ws + 41943040);
    unsigned short* hsl   = (unsigned short*)(ws + 50331648);

    // slot 0 = h0 = 0 (valid); slots 1..128 poisoned 0xFFFF — every call
    hipMemsetAsync(hsl, 0, 65536, stream);
    hipMemsetAsync((char*)hsl + 65536, 0xFF, 8454144 - 65536, stream);

    k_prep<<<256 + 2048, 256, 0, stream>>>(U, ub_hi, ub_lo,
                                           inputs, emb, W, bias, xWb);
    k_fused<<<NB + 4000, 512, 0, stream>>>(ub_hi, ub_lo, xWb, hsl, Wc, bc, out);
}